// Round 13
// baseline (484.348 us; speedup 1.0000x reference)
//
#include <hip/hip_runtime.h>
#include <hip/hip_bf16.h>

#define BB 2
#define SS 2048
#define DD 768
#define HH 12
#define HD 64
#define DFF 3072
#define NROW (BB * SS)   // 4096
#define QLD  2304        // fused QKV row stride
#define LN_EPS 1e-5f
#define NSPLIT 4         // attention split-K factor (4 = measured optimum)

typedef __attribute__((ext_vector_type(8))) short bf16x8;   // 8 bf16 in 4 VGPRs
typedef __attribute__((ext_vector_type(4))) short bf16x4;
typedef __attribute__((ext_vector_type(4))) float f32x4;

__device__ __forceinline__ void gll16(const void* g, void* l) {
    __builtin_amdgcn_global_load_lds(
        (const __attribute__((address_space(1))) unsigned int*)g,
        (__attribute__((address_space(3))) unsigned int*)l,
        16, 0, 0);
}

__device__ __forceinline__ unsigned short bf16bits(float f) {
    __hip_bfloat16 h = __float2bfloat16(f);
    return *(unsigned short*)&h;
}

__device__ __forceinline__ float bf16tof(unsigned short u) {
    unsigned int ui = ((unsigned int)u) << 16;
    return __uint_as_float(ui);
}

// ---------------- block-wide reductions (256 threads = 4 waves of 64) -------
__device__ __forceinline__ float block_sum(float v, float* red) {
    __syncthreads();
    #pragma unroll
    for (int off = 32; off > 0; off >>= 1) v += __shfl_down(v, off, 64);
    if ((threadIdx.x & 63) == 0) red[threadIdx.x >> 6] = v;
    __syncthreads();
    if (threadIdx.x == 0) red[0] = red[0] + red[1] + red[2] + red[3];
    __syncthreads();
    return red[0];
}

// ---------------- bf16 MFMA GEMM: BK=64, XOR-swizzled LDS, XCD swizzle ------
// (round-11 verified; used for Wo and FF2 whose N=768 grids are too small
// for the 256x256 tile)
template<int TM, int TN>
__global__ __launch_bounds__(256) void mfma_gemm(
        const __hip_bfloat16* __restrict__ A, const __hip_bfloat16* __restrict__ BT,
        const float* __restrict__ bias, float* __restrict__ Cf,
        __hip_bfloat16* __restrict__ Cb,
        int N, int K, int relu, int bf16out, int qscale_cols) {
    constexpr int BK = 64;
    constexpr int MW = TM / 32;
    constexpr int NW = TN / 32;
    __shared__ __hip_bfloat16 a_s[TM * BK];
    __shared__ __hip_bfloat16 b_s[TN * BK];

    const int tid  = threadIdx.x;
    const int lane = tid & 63;
    const int wid  = tid >> 6;
    const int wm   = (wid & 1) * (TM / 2);
    const int wn   = (wid >> 1) * (TN / 2);
    const int qq   = lane & 15;
    const int quad = lane >> 4;

    // T1 XCD swizzle (nwg % 8 == 0 for all instantiations)
    const int nwg  = (int)(gridDim.x * gridDim.y);
    const int dlin = (int)blockIdx.x + (int)gridDim.x * (int)blockIdx.y;
    const int wsw  = (dlin & 7) * (nwg >> 3) + (dlin >> 3);
    const int m0 = (wsw / (int)gridDim.x) * TM;
    const int n0 = (wsw % (int)gridDim.x) * TN;

    // staging: per round 256 thr cover 32 rows x 64 cols; wave w rows +w*8
    const int r8   = lane >> 3;            // row within 8-row group (== row&7)
    const int u8   = lane & 7;             // 16B unit within row
    const int gcol = ((u8 ^ r8) << 3);     // swizzled source column

    f32x4 acc[MW][NW] = {};

    for (int k0 = 0; k0 < K; k0 += BK) {
        const __hip_bfloat16* Ag = A + (size_t)m0 * K + k0 + gcol;
        #pragma unroll
        for (int i = 0; i < TM / 32; i++) {
            const int row = i * 32 + wid * 8 + r8;
            gll16(Ag + (size_t)row * K, a_s + row * BK + u8 * 8);
        }
        const __hip_bfloat16* Bg = BT + (size_t)n0 * K + k0 + gcol;
        #pragma unroll
        for (int i = 0; i < TN / 32; i++) {
            const int row = i * 32 + wid * 8 + r8;
            gll16(Bg + (size_t)row * K, b_s + row * BK + u8 * 8);
        }
        __syncthreads();

        #pragma unroll
        for (int kh = 0; kh < 2; kh++) {
            const int ku = kh * 4 + quad;            // 16B unit pre-swizzle
            bf16x8 af[MW], bfr[NW];
            #pragma unroll
            for (int mi = 0; mi < MW; mi++) {
                const int row = wm + mi * 16 + qq;
                af[mi] = *(const bf16x8*)(a_s + row * BK + ((ku ^ (qq & 7)) << 3));
            }
            #pragma unroll
            for (int ni = 0; ni < NW; ni++) {
                const int row = wn + ni * 16 + qq;
                bfr[ni] = *(const bf16x8*)(b_s + row * BK + ((ku ^ (qq & 7)) << 3));
            }
            #pragma unroll
            for (int mi = 0; mi < MW; mi++)
                #pragma unroll
                for (int ni = 0; ni < NW; ni++)
                    acc[mi][ni] = __builtin_amdgcn_mfma_f32_16x16x32_bf16(
                            af[mi], bfr[ni], acc[mi][ni], 0, 0, 0);
        }
        __syncthreads();
    }

    #pragma unroll
    for (int mi = 0; mi < MW; mi++) {
        #pragma unroll
        for (int ni = 0; ni < NW; ni++) {
            const int col = n0 + wn + ni * 16 + qq;
            const float bv = bias[col];
            const float sc = (col < qscale_cols) ? 0.125f : 1.0f;
            #pragma unroll
            for (int r = 0; r < 4; r++) {
                const int row = m0 + wm + mi * 16 + quad * 4 + r;
                float v = acc[mi][ni][r] + bv;
                if (relu) v = fmaxf(v, 0.f);
                v *= sc;
                if (bf16out) Cb[(size_t)row * N + col] = __float2bfloat16(v);
                else         Cf[(size_t)row * N + col] = v;
            }
        }
    }
}

// ---------------- 256x256 8-wave 2-phase GEMM (T3 minimum recipe) -----------
// For the big-N GEMMs (FF1: 192 blocks, QKV: 144). 512 thr = 8 waves (2M x
// 4N); per-wave output 128x64 (acc[8][4]); LDS 128KB double-buffered ->
// 1 block/CU (8 waves supply the TLP). One barrier per K-step: stage(t+1)
// issued BEFORE compute(t), __syncthreads (= vmcnt(0)+barrier) drains it
// after MFMA, so stage latency hides under ~64 MFMA/wave of compute.
// LDS swizzle identical to mfma_gemm; T1 XCD swizzle (grids % 8 == 0).
__global__ __launch_bounds__(512) void mfma_gemm_256(
        const __hip_bfloat16* __restrict__ A, const __hip_bfloat16* __restrict__ BT,
        const float* __restrict__ bias, __hip_bfloat16* __restrict__ Cb,
        int N, int K, int relu, int qscale_cols) {
    constexpr int BK = 64;
    __shared__ __hip_bfloat16 a_s[2][256 * BK];   // 32KB x2
    __shared__ __hip_bfloat16 b_s[2][256 * BK];   // 32KB x2 -> 128KB total

    const int tid  = threadIdx.x;
    const int lane = tid & 63;
    const int wid  = tid >> 6;           // 0..7
    const int wm   = (wid >> 2) * 128;   // 2 M-wave rows
    const int wn   = (wid & 3) * 64;     // 4 N-wave cols
    const int qq   = lane & 15;
    const int quad = lane >> 4;

    // T1 XCD swizzle
    const int gx   = (int)gridDim.x;
    const int nwg  = gx * (int)gridDim.y;
    const int dlin = (int)blockIdx.x + gx * (int)blockIdx.y;
    const int wsw  = (dlin & 7) * (nwg >> 3) + (dlin >> 3);
    const int m0 = (wsw / gx) * 256;
    const int n0 = (wsw % gx) * 256;

    // staging: 512 thr cover 64 rows x 64 cols per round; 4 rounds per tile
    const int srow = tid >> 3;           // 0..63
    const int u8   = tid & 7;
    const int gcol = ((u8 ^ (srow & 7)) << 3);   // pre-swizzled source col

    auto stage = [&](int buf, int k0) {
        const __hip_bfloat16* Ag = A + (size_t)m0 * K + k0 + gcol;
        #pragma unroll
        for (int i = 0; i < 4; i++) {
            const int row = i * 64 + srow;
            gll16(Ag + (size_t)row * K, &a_s[buf][row * BK + u8 * 8]);
        }
        const __hip_bfloat16* Bg = BT + (size_t)n0 * K + k0 + gcol;
        #pragma unroll
        for (int i = 0; i < 4; i++) {
            const int row = i * 64 + srow;
            gll16(Bg + (size_t)row * K, &b_s[buf][row * BK + u8 * 8]);
        }
    };

    f32x4 acc[8][4] = {};
    const int NT = K / BK;

    stage(0, 0);
    __syncthreads();                      // prologue drain
    int cur = 0;
    for (int t = 0; t < NT; t++) {
        if (t + 1 < NT) stage(cur ^ 1, (t + 1) * BK);   // next tile in flight
        const __hip_bfloat16* as = a_s[cur];
        const __hip_bfloat16* bs = b_s[cur];
        #pragma unroll
        for (int kh = 0; kh < 2; kh++) {
            const int ko = ((kh * 4 + quad) ^ (qq & 7)) << 3;
            bf16x8 af[8], bfr[4];
            #pragma unroll
            for (int mi = 0; mi < 8; mi++)
                af[mi] = *(const bf16x8*)(as + (wm + mi * 16 + qq) * BK + ko);
            #pragma unroll
            for (int ni = 0; ni < 4; ni++)
                bfr[ni] = *(const bf16x8*)(bs + (wn + ni * 16 + qq) * BK + ko);
            __builtin_amdgcn_s_setprio(1);
            #pragma unroll
            for (int mi = 0; mi < 8; mi++)
                #pragma unroll
                for (int ni = 0; ni < 4; ni++)
                    acc[mi][ni] = __builtin_amdgcn_mfma_f32_16x16x32_bf16(
                            af[mi], bfr[ni], acc[mi][ni], 0, 0, 0);
            __builtin_amdgcn_s_setprio(0);
        }
        __syncthreads();   // = s_waitcnt vmcnt(0) lgkmcnt(0); s_barrier:
        cur ^= 1;          // next stage complete AND all reads of cur done
    }

    #pragma unroll
    for (int mi = 0; mi < 8; mi++) {
        #pragma unroll
        for (int ni = 0; ni < 4; ni++) {
            const int col = n0 + wn + ni * 16 + qq;
            const float bv = bias[col];
            const float sc = (col < qscale_cols) ? 0.125f : 1.0f;
            #pragma unroll
            for (int r = 0; r < 4; r++) {
                const int row = m0 + wm + mi * 16 + quad * 4 + r;
                float v = acc[mi][ni][r] + bv;
                if (relu) v = fmaxf(v, 0.f);
                Cb[(size_t)row * N + col] = __float2bfloat16(v * sc);
            }
        }
    }
}

// ---------------- fused prep: 6 weight transposes + bias concat + x cvt -----
__device__ __forceinline__ void transpose_tile(
        const float* __restrict__ in, __hip_bfloat16* __restrict__ out,
        int K, int N, int tix, int tiy, float (*t)[33]) {
    const int n0 = tix * 32;
    const int k0 = tiy * 32;
    const int r = threadIdx.x >> 3;
    const int c = threadIdx.x & 7;
    float4 v = *(const float4*)&in[(size_t)(k0 + r) * N + n0 + c * 4];
    t[r][c * 4 + 0] = v.x;
    t[r][c * 4 + 1] = v.y;
    t[r][c * 4 + 2] = v.z;
    t[r][c * 4 + 3] = v.w;
    __syncthreads();
    union { unsigned short u[4]; uint2 w; } pk;
    #pragma unroll
    for (int j = 0; j < 4; j++) pk.u[j] = bf16bits(t[c * 4 + j][r]);
    *(uint2*)&out[(size_t)(n0 + r) * K + k0 + c * 4] = pk.w;
}

__global__ __launch_bounds__(256) void prep_kernel(
        const float* __restrict__ Wq, const float* __restrict__ Wk,
        const float* __restrict__ Wv, const float* __restrict__ Wo,
        const float* __restrict__ W1, const float* __restrict__ W2,
        const float* __restrict__ bq, const float* __restrict__ bk,
        const float* __restrict__ bv, const float* __restrict__ x,
        __hip_bfloat16* __restrict__ WqkvT, __hip_bfloat16* __restrict__ WoT,
        __hip_bfloat16* __restrict__ W1T, __hip_bfloat16* __restrict__ W2T,
        float* __restrict__ biasc, __hip_bfloat16* __restrict__ xb) {
    __shared__ float t[32][33];
    const int bx = blockIdx.x;
    if (bx < 2304) {                       // 4 square 768x768 weights
        const int wsel = bx / 576;
        const int r = bx - wsel * 576;     // 24x24 tiles
        const float* in = (wsel == 0) ? Wq : (wsel == 1) ? Wk : (wsel == 2) ? Wv : Wo;
        __hip_bfloat16* out = (wsel == 3) ? WoT : WqkvT + (size_t)wsel * DD * DD;
        transpose_tile(in, out, DD, DD, r % 24, r / 24, t);
    } else if (bx < 4608) {                // W1: K=DD, N=DFF, 96x24 tiles
        const int r = bx - 2304;
        transpose_tile(W1, W1T, DD, DFF, r % 96, r / 96, t);
    } else if (bx < 6912) {                // W2: K=DFF, N=DD, 24x96 tiles
        const int r = bx - 4608;
        transpose_tile(W2, W2T, DFF, DD, r % 24, r / 24, t);
    } else if (bx < 9984) {                // x -> bf16, 4 elems/thread
        const int i = (bx - 6912) * 256 + threadIdx.x;
        float4 v = ((const float4*)x)[i];
        union { unsigned short u[4]; uint2 w; } pk;
        pk.u[0] = bf16bits(v.x); pk.u[1] = bf16bits(v.y);
        pk.u[2] = bf16bits(v.z); pk.u[3] = bf16bits(v.w);
        ((uint2*)xb)[i] = pk.w;
    } else {                               // bias concat
        const int i = (bx - 9984) * 256 + threadIdx.x;
        if (i < QLD)
            biasc[i] = (i < DD) ? bq[i] : ((i < 2 * DD) ? bk[i - DD] : bv[i - 2 * DD]);
    }
}

// ---------------- MFMA flash attention v9: split-K x4 + XCD swizzle ---------
// (round-11 verified configuration, unchanged)
__global__ __launch_bounds__(256) void flash_attn_kernel(
        const __hip_bfloat16* __restrict__ QKV, const float* __restrict__ alibi,
        __hip_bfloat16* __restrict__ Opart, float* __restrict__ ml) {
    const int gx   = (int)gridDim.x;                 // 128
    const int nwg  = gx * (int)(gridDim.y * gridDim.z);   // 3072
    const int dlin = (int)blockIdx.x +
                     gx * ((int)blockIdx.y + (int)gridDim.y * (int)blockIdx.z);
    const int wsw  = (dlin & 7) * (nwg >> 3) + (dlin >> 3);
    const int rb   = wsw % gx;                       // 0..127 within (h,b)
    const int hb   = wsw / gx;
    const int h    = hb % HH;
    const int b    = hb / HH;
    const int qt   = gx / NSPLIT - 1 - rb / NSPLIT;  // heavy blocks first
    const int s    = rb & (NSPLIT - 1);

    const int tid  = threadIdx.x;
    const int lane = tid & 63;
    const int w    = tid >> 6;
    const int qq   = lane & 15;
    const int quad = lane >> 4;
    const int q0   = qt * 64;

    __shared__ unsigned short K_s[64 * 72];   // [key][d]
    __shared__ unsigned short V_t[64 * 72];   // [d][key]
    __shared__ unsigned short P_t[4][16 * 72];// per-wave [q_local16][key]

    // Q fragments (B operand), per wave: rows q0 + w*16 + qq
    const size_t qrow = ((size_t)(b * SS + q0 + w * 16 + qq)) * QLD + (size_t)h * HD;
    const bf16x8 qf0 = *(const bf16x8*)(QKV + qrow + quad * 8);
    const bf16x8 qf1 = *(const bf16x8*)(QKV + qrow + 32 + quad * 8);

    f32x4 O[4] = {};
    float m_i = -1e30f, l_i = 0.f;

    // alibi row for THIS lane's q (consumer layout, f32, no staging)
    const float* alrow = alibi + ((size_t)h * SS + q0 + w * 16 + qq) * SS;
    const size_t kvrow0 = (size_t)(b * SS) * QLD + (size_t)h * HD + w * 16;
    const int lim = q0 + w * 16 + qq;    // key valid iff k0+key <= lim

    for (int t = s; t * 64 <= q0; t += NSPLIT) {
        const int k0 = t * 64;
        __syncthreads();   // previous iteration's LDS reads complete

        // ---- cooperative staging: thread (w, lane): key-row = lane, chunk = w*16
        {
            const size_t kv = kvrow0 + (size_t)(k0 + lane) * QLD;
            bf16x8 kv0 = *(const bf16x8*)(QKV + DD + kv);
            bf16x8 kv1 = *(const bf16x8*)(QKV + DD + kv + 8);
            *(bf16x8*)&K_s[lane * 72 + w * 16]     = kv0;
            *(bf16x8*)&K_s[lane * 72 + w * 16 + 8] = kv1;
            bf16x8 vv0 = *(const bf16x8*)(QKV + 2 * DD + kv);
            bf16x8 vv1 = *(const bf16x8*)(QKV + 2 * DD + kv + 8);
            #pragma unroll
            for (int j = 0; j < 8; j++) {
                V_t[(w * 16 + j) * 72 + lane]     = vv0[j];
                V_t[(w * 16 + 8 + j) * 72 + lane] = vv1[j];
            }
        }
        __syncthreads();

        // ---- alibi: direct per-lane f32, consumer layout (overlaps QK^T)
        float4 av[4];
        #pragma unroll
        for (int c = 0; c < 4; c++)
            av[c] = *(const float4*)(alrow + k0 + c * 16 + quad * 4);

        // ---- S^T = K.Q^T : 4 key-chunks of 16
        __builtin_amdgcn_s_setprio(1);
        f32x4 S[4];
        #pragma unroll
        for (int c = 0; c < 4; c++) {
            f32x4 sacc = {};
            bf16x8 kf0 = *(const bf16x8*)&K_s[(c * 16 + qq) * 72 + quad * 8];
            bf16x8 kf1 = *(const bf16x8*)&K_s[(c * 16 + qq) * 72 + 32 + quad * 8];
            sacc = __builtin_amdgcn_mfma_f32_16x16x32_bf16(kf0, qf0, sacc, 0, 0, 0);
            sacc = __builtin_amdgcn_mfma_f32_16x16x32_bf16(kf1, qf1, sacc, 0, 0, 0);
            S[c] = sacc;
        }
        __builtin_amdgcn_s_setprio(0);

        // ---- scores: + alibi (f32 direct), causal mask
        float sv[16];
        float smax = -1e30f;
        const int klim = lim - k0;
        #pragma unroll
        for (int c = 0; c < 4; c++) {
            #pragma unroll
            for (int r = 0; r < 4; r++) {
                const int key = c * 16 + quad * 4 + r;
                float sc = S[c][r] + ((const float*)&av[c])[r];
                if (key > klim) sc = -1e30f;
                sv[c * 4 + r] = sc;
                smax = fmaxf(smax, sc);
            }
        }
        smax = fmaxf(smax, __shfl_xor(smax, 16));
        smax = fmaxf(smax, __shfl_xor(smax, 32));

        const float nm = fmaxf(m_i, smax);
        const float alpha = __expf(m_i - nm);
        float lsum = 0.f;
        #pragma unroll
        for (int i = 0; i < 16; i++) {
            const float e = __expf(sv[i] - nm);
            sv[i] = e;
            lsum += e;
        }
        lsum += __shfl_xor(lsum, 16);
        lsum += __shfl_xor(lsum, 32);
        l_i = l_i * alpha + lsum;
        m_i = nm;

        // ---- write P (bf16) to per-wave LDS tile [q][key], packed b64
        #pragma unroll
        for (int c = 0; c < 4; c++) {
            bf16x4 pk;
            #pragma unroll
            for (int r = 0; r < 4; r++) pk[r] = (short)bf16bits(sv[c * 4 + r]);
            *(bf16x4*)&P_t[w][qq * 72 + c * 16 + quad * 4] = pk;
        }

        // ---- rescale O by alpha (per q = quad*4+r rows)
        #pragma unroll
        for (int r = 0; r < 4; r++) {
            const float ar = __shfl(alpha, quad * 4 + r);
            #pragma unroll
            for (int d = 0; d < 4; d++) O[d][r] *= ar;
        }

        // ---- PV: P (A) x V (B), keys in halves of 32
        const bf16x8 pf0 = *(const bf16x8*)&P_t[w][qq * 72 + quad * 8];
        const bf16x8 pf1 = *(const bf16x8*)&P_t[w][qq * 72 + 32 + quad * 8];
        __builtin_amdgcn_s_setprio(1);
        #pragma unroll
        for (int d0 = 0; d0 < 4; d0++) {
            bf16x8 vf0 = *(const bf16x8*)&V_t[(d0 * 16 + qq) * 72 + quad * 8];
            bf16x8 vf1 = *(const bf16x8*)&V_t[(d0 * 16 + qq) * 72 + 32 + quad * 8];
            O[d0] = __builtin_amdgcn_mfma_f32_16x16x32_bf16(pf0, vf0, O[d0], 0, 0, 0);
            O[d0] = __builtin_amdgcn_mfma_f32_16x16x32_bf16(pf1, vf1, O[d0], 0, 0, 0);
        }
        __builtin_amdgcn_s_setprio(0);
    }

    // ---- epilogue: store UNNORMALIZED partials + (m, l)
    if (quad == 0) {
        float* mlp = ml + (((size_t)(b * SS + q0 + w * 16 + qq) * HH + h) * NSPLIT + s) * 2;
        mlp[0] = m_i;
        mlp[1] = l_i;
    }
    #pragma unroll
    for (int r = 0; r < 4; r++) {
        const int row = q0 + w * 16 + quad * 4 + r;
        __hip_bfloat16* op = Opart +
            (((size_t)(b * SS + row) * HH + h) * NSPLIT + s) * 64 + qq;
        op[0]  = __float2bfloat16(O[0][r]);
        op[16] = __float2bfloat16(O[1][r]);
        op[32] = __float2bfloat16(O[2][r]);
        op[48] = __float2bfloat16(O[3][r]);
    }
}

// ---------------- split-K combine -------------------------------------------
__global__ __launch_bounds__(256) void attn_combine_kernel(
        const __hip_bfloat16* __restrict__ Opart, const float* __restrict__ ml,
        __hip_bfloat16* __restrict__ attnb) {
    const int idx = blockIdx.x * 256 + threadIdx.x;   // 0 .. 4096*96-1
    const int rr  = idx / 96;
    const int rem = idx - rr * 96;
    const int h   = rem >> 3;
    const int d8  = (rem & 7) * 8;
    const size_t base = ((size_t)rr * HH + h) * NSPLIT;
    float ms[NSPLIT], ls[NSPLIT];
    float m = -1e30f;
    #pragma unroll
    for (int s = 0; s < NSPLIT; s++) {
        ms[s] = ml[(base + s) * 2];
        ls[s] = ml[(base + s) * 2 + 1];
        m = fmaxf(m, ms[s]);
    }
    float es[NSPLIT], denom = 0.f;
    #pragma unroll
    for (int s = 0; s < NSPLIT; s++) {
        es[s] = __expf(ms[s] - m);
        denom += ls[s] * es[s];
    }
    const float inv = 1.f / denom;
    float acc[8] = {};
    #pragma unroll
    for (int s = 0; s < NSPLIT; s++) {
        const bf16x8 o = *(const bf16x8*)(Opart + (base + s) * 64 + d8);
        #pragma unroll
        for (int j = 0; j < 8; j++)
            acc[j] += bf16tof((unsigned short)o[j]) * es[s];
    }
    union { unsigned short u[8]; bf16x8 v; } pk;
    #pragma unroll
    for (int j = 0; j < 8; j++) pk.u[j] = bf16bits(acc[j] * inv);
    *(bf16x8*)(attnb + (size_t)rr * DD + h * 64 + d8) = pk.v;
}

// ---------------- residual add + layernorm ----------------------------------
__global__ __launch_bounds__(256) void ln_kernel(
        const float* __restrict__ a, const float* __restrict__ r,
        const float* __restrict__ g, const float* __restrict__ beta,
        float* __restrict__ outf, __hip_bfloat16* __restrict__ outb) {
    const int row = blockIdx.x;
    const int tid = threadIdx.x;
    __shared__ float red[64];

    float vals[3];
    float s = 0.f;
    #pragma unroll
    for (int i = 0; i < 3; i++) {
        const int col = i * 256 + tid;
        float t = a[(size_t)row * DD + col] + r[(size_t)row * DD + col];
        vals[i] = t;
        s += t;
    }
    const float mean = block_sum(s, red) * (1.f / DD);

    float s2 = 0.f;
    #pragma unroll
    for (int i = 0; i < 3; i++) {
        float d = vals[i] - mean;
        s2 += d * d;
    }
    const float var = block_sum(s2, red) * (1.f / DD);
    const float rstd = rsqrtf(var + LN_EPS);

    #pragma unroll
    for (int i = 0; i < 3; i++) {
        const int col = i * 256 + tid;
        const float o = (vals[i] - mean) * rstd * g[col] + beta[col];
        outf[(size_t)row * DD + col] = o;
        if (outb) outb[(size_t)row * DD + col] = __float2bfloat16(o);
    }
}

extern "C" void kernel_launch(void* const* d_in, const int* in_sizes, int n_in,
                              void* d_out, int out_size, void* d_ws, size_t ws_size,
                              hipStream_t stream) {
    const float* x     = (const float*)d_in[0];
    const float* alibi = (const float*)d_in[1];
    const float* Wq = (const float*)d_in[2];
    const float* bq = (const float*)d_in[3];
    const float* Wk = (const float*)d_in[4];
    const float* bk = (const float*)d_in[5];
    const float* Wv = (const float*)d_in[6];
    const float* bv = (const float*)d_in[7];
    const float* Wo = (const float*)d_in[8];
    const float* bo = (const float*)d_in[9];
    const float* W1 = (const float*)d_in[10];
    const float* b1 = (const float*)d_in[11];
    const float* W2 = (const float*)d_in[12];
    const float* b2 = (const float*)d_in[13];
    const float* g1 = (const float*)d_in[14];
    const float* be1 = (const float*)d_in[15];
    const float* g2 = (const float*)d_in[16];
    const float* be2 = (const float*)d_in[17];
    float* out = (float*)d_out;

    char* p = (char*)d_ws;
    auto alloc = [&](size_t bytes) { char* r = p; p += (bytes + 255) & ~(size_t)255; return r; };
    __hip_bfloat16* WqkvT = (__hip_bfloat16*)alloc((size_t)QLD * DD * 2);
    __hip_bfloat16* WoT   = (__hip_bfloat16*)alloc((size_t)DD * DD * 2);
    __hip_bfloat16* W1T   = (__hip_bfloat16*)alloc((size_t)DFF * DD * 2);
    __hip_bfloat16* W2T   = (__hip_bfloat16*)alloc((size_t)DD * DFF * 2);
    float*          biasc = (float*)alloc((size_t)QLD * 4);
    __hip_bfloat16* xb    = (__hip_bfloat16*)alloc((size_t)NROW * DD * 2);
    __hip_bfloat16* qkvb  = (__hip_bfloat16*)alloc((size_t)NROW * DFF * 2);
    __hip_bfloat16* attnb = (__hip_bfloat16*)alloc((size_t)NROW * DD * 2);
    float*          proj  = (float*)alloc((size_t)NROW * DD * 4);
    float*          ln1   = (float*)alloc((size_t)NROW * DD * 4);
    __hip_bfloat16* ln1b  = xb;
    __hip_bfloat16* ff1b  = qkvb;
    float*          ff2   = proj;

    // split-K scratch, aliased onto regions dead during attention (round-8
    // verified config): Opart = 25.2 MB = proj+ln1; ml = 1.5 MB in xb.
    __hip_bfloat16* Opart = (__hip_bfloat16*)proj;
    float*          mlbuf = (float*)xb;

    const dim3 blk(256);
    const dim3 blk512(512);

    prep_kernel<<<dim3(9993), blk, 0, stream>>>(
            Wq, Wk, Wv, Wo, W1, W2, bq, bk, bv, x,
            WqkvT, WoT, W1T, W2T, biasc, xb);

    // QKV: 256x256 2-phase -> 9x16 = 144 blocks
    mfma_gemm_256<<<dim3(QLD / 256, NROW / 256), blk512, 0, stream>>>(
            xb, WqkvT, biasc, qkvb, QLD, DD, 0, DD);

    flash_attn_kernel<<<dim3(NSPLIT * (SS / 64), HH, BB), blk, 0, stream>>>(
            qkvb, alibi, Opart, mlbuf);
    attn_combine_kernel<<<dim3(NROW * 96 / 256), blk, 0, stream>>>(
            Opart, mlbuf, attnb);

    // Wo: 64x64 tile -> 768 blocks
    mfma_gemm<64, 64><<<dim3(DD / 64, NROW / 64), blk, 0, stream>>>(
            attnb, WoT, bo, proj, nullptr, DD, DD, 0, 0, 0);

    ln_kernel<<<dim3(NROW), blk, 0, stream>>>(x, proj, g1, be1, ln1, ln1b);

    // FF1: 256x256 2-phase -> 12x16 = 192 blocks
    mfma_gemm_256<<<dim3(DFF / 256, NROW / 256), blk512, 0, stream>>>(
            ln1b, W1T, b1, ff1b, DFF, DD, 1, 0);
    // FF2: 64x64 tile -> 768 blocks
    mfma_gemm<64, 64><<<dim3(DD / 64, NROW / 64), blk, 0, stream>>>(
            ff1b, W2T, b2, ff2, nullptr, DD, DFF, 0, 0, 0);

    ln_kernel<<<dim3(NROW), blk, 0, stream>>>(ln1, ff2, g2, be2, out, nullptr);
}

// Round 14
// 463.503 us; speedup vs baseline: 1.0450x; 1.0450x over previous
//
#include <hip/hip_runtime.h>
#include <hip/hip_bf16.h>

#define BB 2
#define SS 2048
#define DD 768
#define HH 12
#define HD 64
#define DFF 3072
#define NROW (BB * SS)   // 4096
#define QLD  2304        // fused QKV row stride
#define LN_EPS 1e-5f
#define NSPLIT 4         // attention split-K factor (4 = measured optimum)

typedef __attribute__((ext_vector_type(8))) short bf16x8;   // 8 bf16 in 4 VGPRs
typedef __attribute__((ext_vector_type(4))) short bf16x4;
typedef __attribute__((ext_vector_type(4))) float f32x4;

__device__ __forceinline__ void gll16(const void* g, void* l) {
    __builtin_amdgcn_global_load_lds(
        (const __attribute__((address_space(1))) unsigned int*)g,
        (__attribute__((address_space(3))) unsigned int*)l,
        16, 0, 0);
}

__device__ __forceinline__ unsigned short bf16bits(float f) {
    __hip_bfloat16 h = __float2bfloat16(f);
    return *(unsigned short*)&h;
}

__device__ __forceinline__ float bf16tof(unsigned short u) {
    unsigned int ui = ((unsigned int)u) << 16;
    return __uint_as_float(ui);
}

// ---------------- block-wide reductions (256 threads = 4 waves of 64) -------
__device__ __forceinline__ float block_sum(float v, float* red) {
    __syncthreads();
    #pragma unroll
    for (int off = 32; off > 0; off >>= 1) v += __shfl_down(v, off, 64);
    if ((threadIdx.x & 63) == 0) red[threadIdx.x >> 6] = v;
    __syncthreads();
    if (threadIdx.x == 0) red[0] = red[0] + red[1] + red[2] + red[3];
    __syncthreads();
    return red[0];
}

// ---------------- bf16 MFMA GEMM: BK=64, XOR-swizzled LDS, XCD swizzle ------
// Round-11 verified (478.8us build): single-buffer 1-phase; T1 XCD swizzle;
// LDS swizzle: 16B-unit u of row r holds global col-unit (u^(r&7)); reads XOR.
// 2-phase variants REJECTED by measurement: 128^2 dbuf (r6, occupancy loss),
// 256^2 8-wave (r13, CU-coverage loss at 144-192 blocks).
template<int TM, int TN>
__global__ __launch_bounds__(256) void mfma_gemm(
        const __hip_bfloat16* __restrict__ A, const __hip_bfloat16* __restrict__ BT,
        const float* __restrict__ bias, float* __restrict__ Cf,
        __hip_bfloat16* __restrict__ Cb,
        int N, int K, int relu, int bf16out, int qscale_cols) {
    constexpr int BK = 64;
    constexpr int MW = TM / 32;
    constexpr int NW = TN / 32;
    __shared__ __hip_bfloat16 a_s[TM * BK];
    __shared__ __hip_bfloat16 b_s[TN * BK];

    const int tid  = threadIdx.x;
    const int lane = tid & 63;
    const int wid  = tid >> 6;
    const int wm   = (wid & 1) * (TM / 2);
    const int wn   = (wid >> 1) * (TN / 2);
    const int qq   = lane & 15;
    const int quad = lane >> 4;

    // T1 XCD swizzle (nwg % 8 == 0 for all instantiations)
    const int nwg  = (int)(gridDim.x * gridDim.y);
    const int dlin = (int)blockIdx.x + (int)gridDim.x * (int)blockIdx.y;
    const int wsw  = (dlin & 7) * (nwg >> 3) + (dlin >> 3);
    const int m0 = (wsw / (int)gridDim.x) * TM;
    const int n0 = (wsw % (int)gridDim.x) * TN;

    // staging: per round 256 thr cover 32 rows x 64 cols; wave w rows +w*8
    const int r8   = lane >> 3;            // row within 8-row group (== row&7)
    const int u8   = lane & 7;             // 16B unit within row
    const int gcol = ((u8 ^ r8) << 3);     // swizzled source column

    f32x4 acc[MW][NW] = {};

    for (int k0 = 0; k0 < K; k0 += BK) {
        const __hip_bfloat16* Ag = A + (size_t)m0 * K + k0 + gcol;
        #pragma unroll
        for (int i = 0; i < TM / 32; i++) {
            const int row = i * 32 + wid * 8 + r8;
            gll16(Ag + (size_t)row * K, a_s + row * BK + u8 * 8);
        }
        const __hip_bfloat16* Bg = BT + (size_t)n0 * K + k0 + gcol;
        #pragma unroll
        for (int i = 0; i < TN / 32; i++) {
            const int row = i * 32 + wid * 8 + r8;
            gll16(Bg + (size_t)row * K, b_s + row * BK + u8 * 8);
        }
        __syncthreads();

        #pragma unroll
        for (int kh = 0; kh < 2; kh++) {
            const int ku = kh * 4 + quad;            // 16B unit pre-swizzle
            bf16x8 af[MW], bfr[NW];
            #pragma unroll
            for (int mi = 0; mi < MW; mi++) {
                const int row = wm + mi * 16 + qq;
                af[mi] = *(const bf16x8*)(a_s + row * BK + ((ku ^ (qq & 7)) << 3));
            }
            #pragma unroll
            for (int ni = 0; ni < NW; ni++) {
                const int row = wn + ni * 16 + qq;
                bfr[ni] = *(const bf16x8*)(b_s + row * BK + ((ku ^ (qq & 7)) << 3));
            }
            #pragma unroll
            for (int mi = 0; mi < MW; mi++)
                #pragma unroll
                for (int ni = 0; ni < NW; ni++)
                    acc[mi][ni] = __builtin_amdgcn_mfma_f32_16x16x32_bf16(
                            af[mi], bfr[ni], acc[mi][ni], 0, 0, 0);
        }
        __syncthreads();
    }

    #pragma unroll
    for (int mi = 0; mi < MW; mi++) {
        #pragma unroll
        for (int ni = 0; ni < NW; ni++) {
            const int col = n0 + wn + ni * 16 + qq;
            const float bv = bias[col];
            const float sc = (col < qscale_cols) ? 0.125f : 1.0f;
            #pragma unroll
            for (int r = 0; r < 4; r++) {
                const int row = m0 + wm + mi * 16 + quad * 4 + r;
                float v = acc[mi][ni][r] + bv;
                if (relu) v = fmaxf(v, 0.f);
                v *= sc;
                if (bf16out) Cb[(size_t)row * N + col] = __float2bfloat16(v);
                else         Cf[(size_t)row * N + col] = v;
            }
        }
    }
}

// ---------------- fused prep: 6 weight transposes + bias concat + x cvt -----
__device__ __forceinline__ void transpose_tile(
        const float* __restrict__ in, __hip_bfloat16* __restrict__ out,
        int K, int N, int tix, int tiy, float (*t)[33]) {
    const int n0 = tix * 32;
    const int k0 = tiy * 32;
    const int r = threadIdx.x >> 3;
    const int c = threadIdx.x & 7;
    float4 v = *(const float4*)&in[(size_t)(k0 + r) * N + n0 + c * 4];
    t[r][c * 4 + 0] = v.x;
    t[r][c * 4 + 1] = v.y;
    t[r][c * 4 + 2] = v.z;
    t[r][c * 4 + 3] = v.w;
    __syncthreads();
    union { unsigned short u[4]; uint2 w; } pk;
    #pragma unroll
    for (int j = 0; j < 4; j++) pk.u[j] = bf16bits(t[c * 4 + j][r]);
    *(uint2*)&out[(size_t)(n0 + r) * K + k0 + c * 4] = pk.w;
}

__global__ __launch_bounds__(256) void prep_kernel(
        const float* __restrict__ Wq, const float* __restrict__ Wk,
        const float* __restrict__ Wv, const float* __restrict__ Wo,
        const float* __restrict__ W1, const float* __restrict__ W2,
        const float* __restrict__ bq, const float* __restrict__ bk,
        const float* __restrict__ bv, const float* __restrict__ x,
        __hip_bfloat16* __restrict__ WqkvT, __hip_bfloat16* __restrict__ WoT,
        __hip_bfloat16* __restrict__ W1T, __hip_bfloat16* __restrict__ W2T,
        float* __restrict__ biasc, __hip_bfloat16* __restrict__ xb) {
    __shared__ float t[32][33];
    const int bx = blockIdx.x;
    if (bx < 2304) {                       // 4 square 768x768 weights
        const int wsel = bx / 576;
        const int r = bx - wsel * 576;     // 24x24 tiles
        const float* in = (wsel == 0) ? Wq : (wsel == 1) ? Wk : (wsel == 2) ? Wv : Wo;
        __hip_bfloat16* out = (wsel == 3) ? WoT : WqkvT + (size_t)wsel * DD * DD;
        transpose_tile(in, out, DD, DD, r % 24, r / 24, t);
    } else if (bx < 4608) {                // W1: K=DD, N=DFF, 96x24 tiles
        const int r = bx - 2304;
        transpose_tile(W1, W1T, DD, DFF, r % 96, r / 96, t);
    } else if (bx < 6912) {                // W2: K=DFF, N=DD, 24x96 tiles
        const int r = bx - 4608;
        transpose_tile(W2, W2T, DFF, DD, r % 24, r / 24, t);
    } else if (bx < 9984) {                // x -> bf16, 4 elems/thread
        const int i = (bx - 6912) * 256 + threadIdx.x;
        float4 v = ((const float4*)x)[i];
        union { unsigned short u[4]; uint2 w; } pk;
        pk.u[0] = bf16bits(v.x); pk.u[1] = bf16bits(v.y);
        pk.u[2] = bf16bits(v.z); pk.u[3] = bf16bits(v.w);
        ((uint2*)xb)[i] = pk.w;
    } else {                               // bias concat
        const int i = (bx - 9984) * 256 + threadIdx.x;
        if (i < QLD)
            biasc[i] = (i < DD) ? bq[i] : ((i < 2 * DD) ? bk[i - DD] : bv[i - 2 * DD]);
    }
}

// ---------------- MFMA flash attention v10: packed V-transpose staging ------
// = round-11 verified config (split-K x4, direct alibi, T1 XCD swizzle) with
// ONE change: V staging re-partitioned to 2 keys x 8 d per thread so the
// transpose writes become 8 packed ds_write_b32 (was 16 scalar ds_write_b16
// at stride 144B). Same bytes loaded, same V_t layout, readers unchanged.
__global__ __launch_bounds__(256) void flash_attn_kernel(
        const __hip_bfloat16* __restrict__ QKV, const float* __restrict__ alibi,
        __hip_bfloat16* __restrict__ Opart, float* __restrict__ ml) {
    const int gx   = (int)gridDim.x;                 // 128
    const int nwg  = gx * (int)(gridDim.y * gridDim.z);   // 3072
    const int dlin = (int)blockIdx.x +
                     gx * ((int)blockIdx.y + (int)gridDim.y * (int)blockIdx.z);
    const int wsw  = (dlin & 7) * (nwg >> 3) + (dlin >> 3);
    const int rb   = wsw % gx;                       // 0..127 within (h,b)
    const int hb   = wsw / gx;
    const int h    = hb % HH;
    const int b    = hb / HH;
    const int qt   = gx / NSPLIT - 1 - rb / NSPLIT;  // heavy blocks first
    const int s    = rb & (NSPLIT - 1);

    const int tid  = threadIdx.x;
    const int lane = tid & 63;
    const int w    = tid >> 6;
    const int qq   = lane & 15;
    const int quad = lane >> 4;
    const int q0   = qt * 64;

    __shared__ unsigned short K_s[64 * 72];   // [key][d]
    __shared__ unsigned short V_t[64 * 72];   // [d][key]
    __shared__ unsigned short P_t[4][16 * 72];// per-wave [q_local16][key]

    // Q fragments (B operand), per wave: rows q0 + w*16 + qq
    const size_t qrow = ((size_t)(b * SS + q0 + w * 16 + qq)) * QLD + (size_t)h * HD;
    const bf16x8 qf0 = *(const bf16x8*)(QKV + qrow + quad * 8);
    const bf16x8 qf1 = *(const bf16x8*)(QKV + qrow + 32 + quad * 8);

    f32x4 O[4] = {};
    float m_i = -1e30f, l_i = 0.f;

    // alibi row for THIS lane's q (consumer layout, f32, no staging)
    const float* alrow = alibi + ((size_t)h * SS + q0 + w * 16 + qq) * SS;
    const size_t vbase = (size_t)(b * SS) * QLD + (size_t)h * HD;
    const int lim = q0 + w * 16 + qq;    // key valid iff k0+key <= lim

    // V staging partition: 2 adjacent keys x 8 d-values per thread
    const int kp = (lane & 31) * 2;            // key pair base (even)
    const int dh = w * 16 + (lane >> 5) * 8;   // 8-wide d-chunk

    for (int t = s; t * 64 <= q0; t += NSPLIT) {
        const int k0 = t * 64;
        __syncthreads();   // previous iteration's LDS reads complete

        // ---- cooperative staging
        {
            // K: thread (w, lane): key-row = lane, d-chunk = w*16 (2x b128)
            const size_t kv = vbase + w * 16 + (size_t)(k0 + lane) * QLD;
            bf16x8 kv0 = *(const bf16x8*)(QKV + DD + kv);
            bf16x8 kv1 = *(const bf16x8*)(QKV + DD + kv + 8);
            *(bf16x8*)&K_s[lane * 72 + w * 16]     = kv0;
            *(bf16x8*)&K_s[lane * 72 + w * 16 + 8] = kv1;
            // V: 2 keys x 8 d -> 8 packed b32 transpose writes
            const size_t vr = vbase + (size_t)(k0 + kp) * QLD + dh;
            bf16x8 va = *(const bf16x8*)(QKV + 2 * DD + vr);
            bf16x8 vb = *(const bf16x8*)(QKV + 2 * DD + vr + QLD);
            #pragma unroll
            for (int j = 0; j < 8; j++) {
                const unsigned int pk =
                    (unsigned int)(unsigned short)va[j] |
                    ((unsigned int)(unsigned short)vb[j] << 16);
                *(unsigned int*)&V_t[(dh + j) * 72 + kp] = pk;
            }
        }
        __syncthreads();

        // ---- alibi: direct per-lane f32, consumer layout (overlaps QK^T)
        float4 av[4];
        #pragma unroll
        for (int c = 0; c < 4; c++)
            av[c] = *(const float4*)(alrow + k0 + c * 16 + quad * 4);

        // ---- S^T = K.Q^T : 4 key-chunks of 16
        __builtin_amdgcn_s_setprio(1);
        f32x4 S[4];
        #pragma unroll
        for (int c = 0; c < 4; c++) {
            f32x4 sacc = {};
            bf16x8 kf0 = *(const bf16x8*)&K_s[(c * 16 + qq) * 72 + quad * 8];
            bf16x8 kf1 = *(const bf16x8*)&K_s[(c * 16 + qq) * 72 + 32 + quad * 8];
            sacc = __builtin_amdgcn_mfma_f32_16x16x32_bf16(kf0, qf0, sacc, 0, 0, 0);
            sacc = __builtin_amdgcn_mfma_f32_16x16x32_bf16(kf1, qf1, sacc, 0, 0, 0);
            S[c] = sacc;
        }
        __builtin_amdgcn_s_setprio(0);

        // ---- scores: + alibi (f32 direct), causal mask
        float sv[16];
        float smax = -1e30f;
        const int klim = lim - k0;
        #pragma unroll
        for (int c = 0; c < 4; c++) {
            #pragma unroll
            for (int r = 0; r < 4; r++) {
                const int key = c * 16 + quad * 4 + r;
                float sc = S[c][r] + ((const float*)&av[c])[r];
                if (key > klim) sc = -1e30f;
                sv[c * 4 + r] = sc;
                smax = fmaxf(smax, sc);
            }
        }
        smax = fmaxf(smax, __shfl_xor(smax, 16));
        smax = fmaxf(smax, __shfl_xor(smax, 32));

        const float nm = fmaxf(m_i, smax);
        const float alpha = __expf(m_i - nm);
        float lsum = 0.f;
        #pragma unroll
        for (int i = 0; i < 16; i++) {
            const float e = __expf(sv[i] - nm);
            sv[i] = e;
            lsum += e;
        }
        lsum += __shfl_xor(lsum, 16);
        lsum += __shfl_xor(lsum, 32);
        l_i = l_i * alpha + lsum;
        m_i = nm;

        // ---- write P (bf16) to per-wave LDS tile [q][key], packed b64
        #pragma unroll
        for (int c = 0; c < 4; c++) {
            bf16x4 pk;
            #pragma unroll
            for (int r = 0; r < 4; r++) pk[r] = (short)bf16bits(sv[c * 4 + r]);
            *(bf16x4*)&P_t[w][qq * 72 + c * 16 + quad * 4] = pk;
        }

        // ---- rescale O by alpha (per q = quad*4+r rows)
        #pragma unroll
        for (int r = 0; r < 4; r++) {
            const float ar = __shfl(alpha, quad * 4 + r);
            #pragma unroll
            for (int d = 0; d < 4; d++) O[d][r] *= ar;
        }

        // ---- PV: P (A) x V (B), keys in halves of 32
        const bf16x8 pf0 = *(const bf16x8*)&P_t[w][qq * 72 + quad * 8];
        const bf16x8 pf1 = *(const bf16x8*)&P_t[w][qq * 72 + 32 + quad * 8];
        __builtin_amdgcn_s_setprio(1);
        #pragma unroll
        for (int d0 = 0; d0 < 4; d0++) {
            bf16x8 vf0 = *(const bf16x8*)&V_t[(d0 * 16 + qq) * 72 + quad * 8];
            bf16x8 vf1 = *(const bf16x8*)&V_t[(d0 * 16 + qq) * 72 + 32 + quad * 8];
            O[d0] = __builtin_amdgcn_mfma_f32_16x16x32_bf16(pf0, vf0, O[d0], 0, 0, 0);
            O[d0] = __builtin_amdgcn_mfma_f32_16x16x32_bf16(pf1, vf1, O[d0], 0, 0, 0);
        }
        __builtin_amdgcn_s_setprio(0);
    }

    // ---- epilogue: store UNNORMALIZED partials + (m, l)
    if (quad == 0) {
        float* mlp = ml + (((size_t)(b * SS + q0 + w * 16 + qq) * HH + h) * NSPLIT + s) * 2;
        mlp[0] = m_i;
        mlp[1] = l_i;
    }
    #pragma unroll
    for (int r = 0; r < 4; r++) {
        const int row = q0 + w * 16 + quad * 4 + r;
        __hip_bfloat16* op = Opart +
            (((size_t)(b * SS + row) * HH + h) * NSPLIT + s) * 64 + qq;
        op[0]  = __float2bfloat16(O[0][r]);
        op[16] = __float2bfloat16(O[1][r]);
        op[32] = __float2bfloat16(O[2][r]);
        op[48] = __float2bfloat16(O[3][r]);
    }
}

// ---------------- split-K combine -------------------------------------------
__global__ __launch_bounds__(256) void attn_combine_kernel(
        const __hip_bfloat16* __restrict__ Opart, const float* __restrict__ ml,
        __hip_bfloat16* __restrict__ attnb) {
    const int idx = blockIdx.x * 256 + threadIdx.x;   // 0 .. 4096*96-1
    const int rr  = idx / 96;
    const int rem = idx - rr * 96;
    const int h   = rem >> 3;
    const int d8  = (rem & 7) * 8;
    const size_t base = ((size_t)rr * HH + h) * NSPLIT;
    float ms[NSPLIT], ls[NSPLIT];
    float m = -1e30f;
    #pragma unroll
    for (int s = 0; s < NSPLIT; s++) {
        ms[s] = ml[(base + s) * 2];
        ls[s] = ml[(base + s) * 2 + 1];
        m = fmaxf(m, ms[s]);
    }
    float es[NSPLIT], denom = 0.f;
    #pragma unroll
    for (int s = 0; s < NSPLIT; s++) {
        es[s] = __expf(ms[s] - m);
        denom += ls[s] * es[s];
    }
    const float inv = 1.f / denom;
    float acc[8] = {};
    #pragma unroll
    for (int s = 0; s < NSPLIT; s++) {
        const bf16x8 o = *(const bf16x8*)(Opart + (base + s) * 64 + d8);
        #pragma unroll
        for (int j = 0; j < 8; j++)
            acc[j] += bf16tof((unsigned short)o[j]) * es[s];
    }
    union { unsigned short u[8]; bf16x8 v; } pk;
    #pragma unroll
    for (int j = 0; j < 8; j++) pk.u[j] = bf16bits(acc[j] * inv);
    *(bf16x8*)(attnb + (size_t)rr * DD + h * 64 + d8) = pk.v;
}

// ---------------- residual add + layernorm ----------------------------------
__global__ __launch_bounds__(256) void ln_kernel(
        const float* __restrict__ a, const float* __restrict__ r,
        const float* __restrict__ g, const float* __restrict__ beta,
        float* __restrict__ outf, __hip_bfloat16* __restrict__ outb) {
    const int row = blockIdx.x;
    const int tid = threadIdx.x;
    __shared__ float red[64];

    float vals[3];
    float s = 0.f;
    #pragma unroll
    for (int i = 0; i < 3; i++) {
        const int col = i * 256 + tid;
        float t = a[(size_t)row * DD + col] + r[(size_t)row * DD + col];
        vals[i] = t;
        s += t;
    }
    const float mean = block_sum(s, red) * (1.f / DD);

    float s2 = 0.f;
    #pragma unroll
    for (int i = 0; i < 3; i++) {
        float d = vals[i] - mean;
        s2 += d * d;
    }
    const float var = block_sum(s2, red) * (1.f / DD);
    const float rstd = rsqrtf(var + LN_EPS);

    #pragma unroll
    for (int i = 0; i < 3; i++) {
        const int col = i * 256 + tid;
        const float o = (vals[i] - mean) * rstd * g[col] + beta[col];
        outf[(size_t)row * DD + col] = o;
        if (outb) outb[(size_t)row * DD + col] = __float2bfloat16(o);
    }
}

extern "C" void kernel_launch(void* const* d_in, const int* in_sizes, int n_in,
                              void* d_out, int out_size, void* d_ws, size_t ws_size,
                              hipStream_t stream) {
    const float* x     = (const float*)d_in[0];
    const float* alibi = (const float*)d_in[1];
    const float* Wq = (const float*)d_in[2];
    const float* bq = (const float*)d_in[3];
    const float* Wk = (const float*)d_in[4];
    const float* bk = (const float*)d_in[5];
    const float* Wv = (const float*)d_in[6];
    const float* bv = (const float*)d_in[7];
    const float* Wo = (const float*)d_in[8];
    const float* bo = (const float*)d_in[9];
    const float* W1 = (const float*)d_in[10];
    const float* b1 = (const float*)d_in[11];
    const float* W2 = (const float*)d_in[12];
    const float* b2 = (const float*)d_in[13];
    const float* g1 = (const float*)d_in[14];
    const float* be1 = (const float*)d_in[15];
    const float* g2 = (const float*)d_in[16];
    const float* be2 = (const float*)d_in[17];
    float* out = (float*)d_out;

    char* p = (char*)d_ws;
    auto alloc = [&](size_t bytes) { char* r = p; p += (bytes + 255) & ~(size_t)255; return r; };
    __hip_bfloat16* WqkvT = (__hip_bfloat16*)alloc((size_t)QLD * DD * 2);
    __hip_bfloat16* WoT   = (__hip_bfloat16*)alloc((size_t)DD * DD * 2);
    __hip_bfloat16* W1T   = (__hip_bfloat16*)alloc((size_t)DFF * DD * 2);
    __hip_bfloat16* W2T   = (__hip_bfloat16*)alloc((size_t)DD * DFF * 2);
    float*          biasc = (float*)alloc((size_t)QLD * 4);
    __hip_bfloat16* xb    = (__hip_bfloat16*)alloc((size_t)NROW * DD * 2);
    __hip_bfloat16* qkvb  = (__hip_bfloat16*)alloc((size_t)NROW * DFF * 2);
    __hip_bfloat16* attnb = (__hip_bfloat16*)alloc((size_t)NROW * DD * 2);
    float*          proj  = (float*)alloc((size_t)NROW * DD * 4);
    float*          ln1   = (float*)alloc((size_t)NROW * DD * 4);
    __hip_bfloat16* ln1b  = xb;
    __hip_bfloat16* ff1b  = qkvb;
    float*          ff2   = proj;

    // split-K scratch, aliased onto regions dead during attention (round-8
    // verified config): Opart = 25.2 MB = proj+ln1; ml = 1.5 MB in xb.
    __hip_bfloat16* Opart = (__hip_bfloat16*)proj;
    float*          mlbuf = (float*)xb;

    const dim3 blk(256);

    prep_kernel<<<dim3(9993), blk, 0, stream>>>(
            Wq, Wk, Wv, Wo, W1, W2, bq, bk, bv, x,
            WqkvT, WoT, W1T, W2T, biasc, xb);

    // QKV: 128x96 tile -> 24x32 = 768 blocks
    mfma_gemm<128, 96><<<dim3(QLD / 96, NROW / 128), blk, 0, stream>>>(
            xb, WqkvT, biasc, nullptr, qkvb, QLD, DD, 0, 1, DD);

    flash_attn_kernel<<<dim3(NSPLIT * (SS / 64), HH, BB), blk, 0, stream>>>(
            qkvb, alibi, Opart, mlbuf);
    attn_combine_kernel<<<dim3(NROW * 96 / 256), blk, 0, stream>>>(
            Opart, mlbuf, attnb);

    // Wo: 64x64 tile -> 768 blocks
    mfma_gemm<64, 64><<<dim3(DD / 64, NROW / 64), blk, 0, stream>>>(
            attnb, WoT, bo, proj, nullptr, DD, DD, 0, 0, 0);

    ln_kernel<<<dim3(NROW), blk, 0, stream>>>(x, proj, g1, be1, ln1, ln1b);

    // FF1: 128x128 -> 768 blocks
    mfma_gemm<128, 128><<<dim3(DFF / 128, NROW / 128), blk, 0, stream>>>(
            ln1b, W1T, b1, nullptr, ff1b, DFF, DD, 1, 1, 0);
    // FF2: 64x64 tile -> 768 blocks
    mfma_gemm<64, 64><<<dim3(DD / 64, NROW / 64), blk, 0, stream>>>(
            ff1b, W2T, b2, ff2, nullptr, DD, DFF, 0, 0, 0);

    ln_kernel<<<dim3(NROW), blk, 0, stream>>>(ln1, ff2, g2, be2, out, nullptr);
}